// Round 7
// baseline (373.251 us; speedup 1.0000x reference)
//
#include <hip/hip_runtime.h>
#include <hip/hip_fp16.h>
#include <stdint.h>

// Problem constants: B=4, S=128 -> M=512
#define M_DIM 512
#define K_DIM 4096
#define N_DIM 11008
#define KT (K_DIM / 64)        // 64 k-tiles of BK=64
#define SK 2                   // split-K
#define NB_M 8                 // 64-row strips
#define NB_N 172               // 64-col strips
#define NBLK (NB_M * NB_N * SK)   // 2752 single-wave blocks
#define ITERS (KT / SK)        // 32 k-tiles per wave (even)

typedef __attribute__((ext_vector_type(8))) _Float16 half8;
typedef __attribute__((ext_vector_type(4))) float floatx4;

__device__ __forceinline__ unsigned int h2u(__half2 h) {
    union { __half2 h; unsigned int u; } c; c.h = h; return c.u;
}
__device__ __forceinline__ __half2 u2h(unsigned int u) {
    union { unsigned int u; __half2 h; } c; c.u = u; return c.h;
}
union U4H8 { uint4 u; half8 h; };

// one packed dword (8 codes, pair-interleaved) -> b-operand half8 (R5-proven)
__device__ __forceinline__ half8 dequant8(unsigned int dw, __half2 s2, __half2 z2) {
    const __half2 kb = u2h(0x64006400u);   // (1024, 1024)
    U4H8 r;
    unsigned int p0 = (dw & 0x000F000Fu) | 0x64006400u;
    unsigned int p1 = ((dw >> 4)  & 0x000F000Fu) | 0x64006400u;
    unsigned int p2 = ((dw >> 8)  & 0x000F000Fu) | 0x64006400u;
    unsigned int p3 = ((dw >> 12) & 0x000F000Fu) | 0x64006400u;
    r.u.x = h2u(__hfma2(__hsub2(u2h(p0), kb), s2, z2));
    r.u.y = h2u(__hfma2(__hsub2(u2h(p1), kb), s2, z2));
    r.u.z = h2u(__hfma2(__hsub2(u2h(p2), kb), s2, z2));
    r.u.w = h2u(__hfma2(__hsub2(u2h(p3), kb), s2, z2));
    return r.h;
}

// ---------------------------------------------------------------------------
// Kernel 1: x fp32 [512,4096] -> f16 in FRAGMENT-LINEAR order (R6 layout).
// ---------------------------------------------------------------------------
__global__ __launch_bounds__(256) void cvt_kernel(
        const float* __restrict__ x, unsigned int* __restrict__ xb) {
    int id = blockIdx.x * 256 + threadIdx.x;   // chunk id, 262144 total
    int m  = id >> 9;
    int kc = id & 511;
    const float4* src = (const float4*)(x + ((size_t)m << 12) + (kc << 3));
    float4 f0 = src[0];
    float4 f1 = src[1];
    uint4 v;
    v.x = h2u(__float22half2_rn(float2{f0.x, f0.y}));
    v.y = h2u(__float22half2_rn(float2{f0.z, f0.w}));
    v.z = h2u(__float22half2_rn(float2{f1.x, f1.y}));
    v.w = h2u(__float22half2_rn(float2{f1.z, f1.w}));
    int tm = m >> 7, r = m & 127, tk = kc >> 3, c = kc & 7;
    int igrp = r >> 4, rlow = r & 15, s01 = c >> 2, q = c & 3;
    int chunk = ((igrp * 2 + s01) << 6) + (q << 4) + rlow;
    size_t dstu = (((size_t)(tm * KT + tk)) << 12) + ((size_t)chunk << 2);
    *((uint4*)(xb + dstu)) = v;
}

// ---------------------------------------------------------------------------
// Kernel 2: pack wq int32 [N,K] -> nibbles, tile-major [nb][kt], within tile
// dword index = q*128 + r; nibbles pair-interleaved (R5-proven).
// ---------------------------------------------------------------------------
__global__ __launch_bounds__(256) void pack_kernel(
        const int* __restrict__ wq, unsigned int* __restrict__ wpk) {
    int id   = blockIdx.x * 256 + threadIdx.x;
    int tile = id >> 9;                         // 5504 tiles (86 nb x 64 kt)
    int p    = id & 511;
    int nb = tile >> 6, kt = tile & 63;
    int r = p >> 2, q0 = (p & 3) * 2;
    const int4* src = (const int4*)(wq + (size_t)(nb * 128 + r) * K_DIM + kt * 64 + q0 * 8);
    int4 a0 = src[0];
    int4 a1 = src[1];
    int4 a2 = src[2];
    int4 a3 = src[3];
    unsigned int u0 =
        (unsigned)a0.x | ((unsigned)a0.z << 4)  | ((unsigned)a1.x << 8)  | ((unsigned)a1.z << 12) |
        ((unsigned)a0.y << 16) | ((unsigned)a0.w << 20) | ((unsigned)a1.y << 24) | ((unsigned)a1.w << 28);
    unsigned int u1 =
        (unsigned)a2.x | ((unsigned)a2.z << 4)  | ((unsigned)a3.x << 8)  | ((unsigned)a3.z << 12) |
        ((unsigned)a2.y << 16) | ((unsigned)a2.w << 20) | ((unsigned)a3.y << 24) | ((unsigned)a3.w << 28);
    size_t base = ((size_t)tile) << 10;
    wpk[base + (q0 << 7) + r]       = u0;
    wpk[base + ((q0 + 1) << 7) + r] = u1;
}

// ---------------------------------------------------------------------------
// Kernel 3: GEMM. One wave per block, 64x64 tile, no LDS, no barriers.
// Manually 2-stage pipelined K-loop: A-frags, W dwords AND scales are all
// loaded one full k-tile (~400 cyc) before first use.
// ---------------------------------------------------------------------------
__global__ __launch_bounds__(64, 3) void gemm_kernel(
        const unsigned int* __restrict__ xb,    // fragment-linear f16 x
        const unsigned int* __restrict__ wpk,   // packed nibbles, [q][r] tiles
        const float*        __restrict__ saz,   // [K/128, N, 2]
        float*              __restrict__ out)   // [M,N] fp32 (pre-zeroed)
{
    const int bx   = blockIdx.x;
    const int mbp  = bx & 7;
    const int rest = bx >> 3;
    const int nbp  = rest % NB_N;
    const int sk   = rest / NB_N;
    const int kt0  = sk * ITERS;
    const int lane = threadIdx.x;
    const int q4   = lane >> 4;
    const int lr   = lane & 15;

    const int tm    = mbp >> 1;
    const int igrp0 = (mbp & 1) * 4;
    const int nbt   = nbp >> 1;
    const int wn    = (nbp & 1) * 64;

    // A fragments: frag (i, s01) at xat[i*128 + s01*64]; +1024 per k-tile
    const half8* xat = (const half8*)xb
        + (((size_t)(tm * KT + kt0)) << 10) + (igrp0 << 7) + lane;

    // W: frag (j, s01) at wbase[s01*512 + j*16]; +1024 dwords per k-tile
    const unsigned int* wbase =
        wpk + (((size_t)(nbt * KT + kt0)) << 10) + (q4 << 7) + wn + lr;

    const float2* saz2 = (const float2*)saz;
    const int nrow0 = nbp * 64 + lr;

    floatx4 acc[4][4];
    floatx4 zero4 = {0.f, 0.f, 0.f, 0.f};
#pragma unroll
    for (int i = 0; i < 4; ++i)
#pragma unroll
        for (int j = 0; j < 4; ++j)
            acc[i][j] = zero4;

    // ---- stage registers
    half8 av0[8], av1[8];
    unsigned int qw0[8], qw1[8];
    __half2 s2[4], z2[4];
    float2 szn[4];

    // prologue: tile kt0 + scales for group kt0>>1
#pragma unroll
    for (int i = 0; i < 4; ++i) {
        av0[i * 2]     = xat[i * 128];
        av0[i * 2 + 1] = xat[i * 128 + 64];
    }
#pragma unroll
    for (int f = 0; f < 8; ++f)
        qw0[f] = wbase[(f >> 2) * 512 + (f & 3) * 16];
    {
        const size_t gbase = (size_t)(kt0 >> 1) * N_DIM + nrow0;
#pragma unroll
        for (int t = 0; t < 4; ++t) {
            float2 f = saz2[gbase + t * 16];
            s2[t] = __float2half2_rn(f.x);
            z2[t] = __float2half2_rn(fmaf(-8.f, f.x, f.y));
        }
    }

    for (int it = 0; it < ITERS; it += 2) {
        // loads for odd tile (it+1) — consumed after compute(av0)
        xat   += 1024;
        wbase += 1024;
#pragma unroll
        for (int i = 0; i < 4; ++i) {
            av1[i * 2]     = xat[i * 128];
            av1[i * 2 + 1] = xat[i * 128 + 64];
        }
#pragma unroll
        for (int f = 0; f < 8; ++f)
            qw1[f] = wbase[(f >> 2) * 512 + (f & 3) * 16];

        // scales for next group (tiles it+2, it+3) — converted at pair end
        if (it + 2 < ITERS) {
            const size_t gbase =
                ((size_t)((kt0 + it) >> 1) + 1) * N_DIM + nrow0;
#pragma unroll
            for (int t = 0; t < 4; ++t)
                szn[t] = saz2[gbase + t * 16];
        }

        // compute tile it (even)
#pragma unroll
        for (int s01 = 0; s01 < 2; ++s01) {
#pragma unroll
            for (int j = 0; j < 4; ++j) {
                half8 bv = dequant8(qw0[s01 * 4 + j], s2[j], z2[j]);
#pragma unroll
                for (int i = 0; i < 4; ++i)
                    acc[i][j] = __builtin_amdgcn_mfma_f32_16x16x32_f16(
                        av0[i * 2 + s01], bv, acc[i][j], 0, 0, 0);
            }
        }

        // loads for next even tile (it+2) — consumed after compute(av1)
        if (it + 2 < ITERS) {
            xat   += 1024;
            wbase += 1024;
#pragma unroll
            for (int i = 0; i < 4; ++i) {
                av0[i * 2]     = xat[i * 128];
                av0[i * 2 + 1] = xat[i * 128 + 64];
            }
#pragma unroll
            for (int f = 0; f < 8; ++f)
                qw0[f] = wbase[(f >> 2) * 512 + (f & 3) * 16];
        }

        // compute tile it+1 (odd, same scale group)
#pragma unroll
        for (int s01 = 0; s01 < 2; ++s01) {
#pragma unroll
            for (int j = 0; j < 4; ++j) {
                half8 bv = dequant8(qw1[s01 * 4 + j], s2[j], z2[j]);
#pragma unroll
                for (int i = 0; i < 4; ++i)
                    acc[i][j] = __builtin_amdgcn_mfma_f32_16x16x32_f16(
                        av1[i * 2 + s01], bv, acc[i][j], 0, 0, 0);
            }
        }

        // convert prefetched scales for the next pair
        if (it + 2 < ITERS) {
#pragma unroll
            for (int t = 0; t < 4; ++t) {
                s2[t] = __float2half2_rn(szn[t].x);
                z2[t] = __float2half2_rn(fmaf(-8.f, szn[t].x, szn[t].y));
            }
        }
    }

    // Epilogue: C/D layout col = lane&15 (n), row = q4*4 + reg (m).
    const int m0 = mbp * 64 + q4 * 4;
    const int n0 = nbp * 64 + lr;
#pragma unroll
    for (int i = 0; i < 4; ++i) {
#pragma unroll
        for (int j = 0; j < 4; ++j) {
            floatx4 v = acc[i][j];
            float* o = out + (size_t)(m0 + i * 16) * N_DIM + (n0 + j * 16);
#pragma unroll
            for (int rr = 0; rr < 4; ++rr)
                __hip_atomic_fetch_add(&o[(size_t)rr * N_DIM], v[rr],
                                       __ATOMIC_RELAXED, __HIP_MEMORY_SCOPE_AGENT);
        }
    }
}

extern "C" void kernel_launch(void* const* d_in, const int* in_sizes, int n_in,
                              void* d_out, int out_size, void* d_ws, size_t ws_size,
                              hipStream_t stream) {
    const float* x   = (const float*)d_in[0];
    const int*   wq  = (const int*)d_in[1];
    const float* saz = (const float*)d_in[2];

    // ws layout: [wpk: 22,544,384 B packed weights][xb: 4 MB f16 x]
    unsigned int* wpk = (unsigned int*)d_ws;
    unsigned int* xb  = (unsigned int*)((char*)d_ws + 22544384);

    hipMemsetAsync(d_out, 0, (size_t)out_size * sizeof(float), stream);
    pack_kernel<<<dim3(11008), dim3(256), 0, stream>>>(wq, wpk);
    cvt_kernel<<<dim3(1024), dim3(256), 0, stream>>>(x, xb);
    gemm_kernel<<<dim3(NBLK), dim3(64), 0, stream>>>(xb, wpk, saz, (float*)d_out);
}

// Round 8
// 370.373 us; speedup vs baseline: 1.0078x; 1.0078x over previous
//
#include <hip/hip_runtime.h>
#include <hip/hip_fp16.h>
#include <stdint.h>

// Problem constants: B=4, S=128 -> M=512
#define M_DIM 512
#define K_DIM 4096
#define N_DIM 11008
#define KT 64                  // k-tiles of BK=64
#define SK 4                   // split-K
#define ITERS (KT / SK)        // 16 k-tiles per block
#define NP 86                  // 128-col n-pairs
#define NBLK (8 * NP * SK)     // 2752 blocks x 128 threads (2 waves)

typedef __attribute__((ext_vector_type(8))) _Float16 half8;
typedef __attribute__((ext_vector_type(4))) float floatx4;

__device__ __forceinline__ unsigned int h2u(__half2 h) {
    union { __half2 h; unsigned int u; } c; c.h = h; return c.u;
}
__device__ __forceinline__ __half2 u2h(unsigned int u) {
    union { unsigned int u; __half2 h; } c; c.u = u; return c.h;
}
union U4H8 { uint4 u; half8 h; };

// one packed dword (8 codes, pair-interleaved) -> b-operand half8 (R5-proven)
__device__ __forceinline__ half8 dequant8(unsigned int dw, __half2 s2, __half2 z2) {
    const __half2 kb = u2h(0x64006400u);   // (1024, 1024)
    U4H8 r;
    unsigned int p0 = (dw & 0x000F000Fu) | 0x64006400u;
    unsigned int p1 = ((dw >> 4)  & 0x000F000Fu) | 0x64006400u;
    unsigned int p2 = ((dw >> 8)  & 0x000F000Fu) | 0x64006400u;
    unsigned int p3 = ((dw >> 12) & 0x000F000Fu) | 0x64006400u;
    r.u.x = h2u(__hfma2(__hsub2(u2h(p0), kb), s2, z2));
    r.u.y = h2u(__hfma2(__hsub2(u2h(p1), kb), s2, z2));
    r.u.z = h2u(__hfma2(__hsub2(u2h(p2), kb), s2, z2));
    r.u.w = h2u(__hfma2(__hsub2(u2h(p3), kb), s2, z2));
    return r.h;
}

// ---------------------------------------------------------------------------
// Kernel 1: x fp32 [512,4096] -> f16 in FRAGMENT-LINEAR order (R6 layout).
// Tile (tm,tk) = 1024 chunks of 16 B; chunk = (igrp*2 + s01)*64 + q*16 + rlow
// for m = tm*128 + igrp*16 + rlow, k = tk*64 + s01*32 + q*8 + j.
// A 64-row half-tile is a contiguous 8 KB region -> linear LDS DMA.
// ---------------------------------------------------------------------------
__global__ __launch_bounds__(256) void cvt_kernel(
        const float* __restrict__ x, unsigned int* __restrict__ xb) {
    int id = blockIdx.x * 256 + threadIdx.x;   // chunk id, 262144 total
    int m  = id >> 9;
    int kc = id & 511;
    const float4* src = (const float4*)(x + ((size_t)m << 12) + (kc << 3));
    float4 f0 = src[0];
    float4 f1 = src[1];
    uint4 v;
    v.x = h2u(__float22half2_rn(float2{f0.x, f0.y}));
    v.y = h2u(__float22half2_rn(float2{f0.z, f0.w}));
    v.z = h2u(__float22half2_rn(float2{f1.x, f1.y}));
    v.w = h2u(__float22half2_rn(float2{f1.z, f1.w}));
    int tm = m >> 7, r = m & 127, tk = kc >> 3, c = kc & 7;
    int igrp = r >> 4, rlow = r & 15, s01 = c >> 2, q = c & 3;
    int chunk = ((igrp * 2 + s01) << 6) + (q << 4) + rlow;
    size_t dstu = (((size_t)(tm * KT + tk)) << 12) + ((size_t)chunk << 2);
    *((uint4*)(xb + dstu)) = v;
}

// ---------------------------------------------------------------------------
// Kernel 2: pack wq int32 [N,K] -> nibbles, tile-major [nb][kt], within tile
// dword index = q*128 + r; nibbles pair-interleaved (R5-proven).
// ---------------------------------------------------------------------------
__global__ __launch_bounds__(256) void pack_kernel(
        const int* __restrict__ wq, unsigned int* __restrict__ wpk) {
    int id   = blockIdx.x * 256 + threadIdx.x;
    int tile = id >> 9;                         // 5504 tiles (86 nb x 64 kt)
    int p    = id & 511;
    int nb = tile >> 6, kt = tile & 63;
    int r = p >> 2, q0 = (p & 3) * 2;
    const int4* src = (const int4*)(wq + (size_t)(nb * 128 + r) * K_DIM + kt * 64 + q0 * 8);
    int4 a0 = src[0];
    int4 a1 = src[1];
    int4 a2 = src[2];
    int4 a3 = src[3];
    unsigned int u0 =
        (unsigned)a0.x | ((unsigned)a0.z << 4)  | ((unsigned)a1.x << 8)  | ((unsigned)a1.z << 12) |
        ((unsigned)a0.y << 16) | ((unsigned)a0.w << 20) | ((unsigned)a1.y << 24) | ((unsigned)a1.w << 28);
    unsigned int u1 =
        (unsigned)a2.x | ((unsigned)a2.z << 4)  | ((unsigned)a3.x << 8)  | ((unsigned)a3.z << 12) |
        ((unsigned)a2.y << 16) | ((unsigned)a2.w << 20) | ((unsigned)a3.y << 24) | ((unsigned)a3.w << 28);
    size_t base = ((size_t)tile) << 10;
    wpk[base + (q0 << 7) + r]       = u0;
    wpk[base + ((q0 + 1) << 7) + r] = u1;
}

// ---------------------------------------------------------------------------
// Kernel 3: GEMM. 128-thread blocks (2 waves sharing one 64-row A tile via
// LDS double-buffer DMA; each wave owns a 64-col n-strip). W dequanted
// in-register from packed nibbles (1 tile ahead); scales 2 tiles ahead.
// Split-K=4, per-iter __syncthreads drain (everything it waits on is one
// full compute phase old). Atomic-f32 epilogue.
// ---------------------------------------------------------------------------
__global__ __launch_bounds__(128, 3) void gemm_kernel(
        const unsigned int* __restrict__ xb,    // fragment-linear f16 x
        const unsigned int* __restrict__ wpk,   // packed nibbles, [q][r] tiles
        const float*        __restrict__ saz,   // [K/128, N, 2]
        float*              __restrict__ out)   // [M,N] fp32 (pre-zeroed)
{
    __shared__ __align__(16) unsigned short sA[2 * 4096];  // 2 x 8 KB

    const int tid  = threadIdx.x;
    const int wave = tid >> 6;
    const int lane = tid & 63;
    const int q4   = lane >> 4;
    const int lr   = lane & 15;

    const int bx    = blockIdx.x;
    const int mbp   = bx & 7;                  // 64-row strip 0..7
    const int rest  = bx >> 3;
    const int npair = rest % NP;               // 128-col pair 0..85
    const int sk    = rest / NP;               // 0..3
    const int kt0   = sk * ITERS;

    const int tm    = mbp >> 1;                // xb 128-row tile
    const int igrp0 = (mbp & 1) * 4;           // 8 KB half-tile select

    // per-lane A global pointer (16 B units); +1024 per k-tile
    const half8* agl = (const half8*)xb
        + (((size_t)(tm * KT + kt0)) << 10) + (igrp0 << 7) + (wave << 8) + lane;

    // W: frag (j,s01) at wbase[s01*512 + j*16]; +1024 dwords per k-tile
    const unsigned int* wbase =
        wpk + (((size_t)(npair * KT + kt0)) << 10) + (q4 << 7) + (wave << 6) + lr;

    const float2* saz2 = (const float2*)saz;
    const int nrow0 = npair * 128 + wave * 64 + lr;

    floatx4 acc[4][4];
    floatx4 zero4 = {0.f, 0.f, 0.f, 0.f};
#pragma unroll
    for (int i = 0; i < 4; ++i)
#pragma unroll
        for (int j = 0; j < 4; ++j)
            acc[i][j] = zero4;

    unsigned int qw[8], qwn[8];
    __half2 s2[4], z2[4];
    float2 szn[4];

    // ---- prologue: DMA tile kt0 -> buf0 (each wave stages its 4 KB)
#pragma unroll
    for (int j = 0; j < 4; ++j) {
        __builtin_amdgcn_global_load_lds(
            (const __attribute__((address_space(1))) unsigned int*)(agl + j * 64),
            (__attribute__((address_space(3))) unsigned int*)(sA + (wave * 4 + j) * 512),
            16, 0, 0);
    }
#pragma unroll
    for (int f = 0; f < 8; ++f)
        qw[f] = wbase[(f >> 2) * 512 + (f & 3) * 16];
    {
        const size_t gbase = (size_t)(kt0 >> 1) * N_DIM + nrow0;
#pragma unroll
        for (int t = 0; t < 4; ++t) {
            float2 f = saz2[gbase + t * 16];
            s2[t] = __float2half2_rn(f.x);
            z2[t] = __float2half2_rn(fmaf(-8.f, f.x, f.y));
        }
    }

    for (int it = 0; it < ITERS; ++it) {
        const int cs = (it & 1) * 4096;        // current LDS base (shorts)

        __syncthreads();   // drains DMA(cur) + qw(it) loads (all ~1 iter old)

        // new scale group every even it (GS=128 = 2 k-tiles); szn loaded 2 ago
        if (it > 0 && (it & 1) == 0) {
#pragma unroll
            for (int t = 0; t < 4; ++t) {
                s2[t] = __float2half2_rn(szn[t].x);
                z2[t] = __float2half2_rn(fmaf(-8.f, szn[t].x, szn[t].y));
            }
        }

        // A fragments from LDS (shared by both waves)
        half8 av[8];
#pragma unroll
        for (int k = 0; k < 8; ++k)
            av[k] = *((const half8*)&sA[cs + ((k << 6) + lane) * 8]);

        // prefetch next k-tile: A-DMA into other buffer + W dwords
        if (it + 1 < ITERS) {
            agl   += 1024;
            wbase += 1024;
            const int ns = ((it + 1) & 1) * 4096;
#pragma unroll
            for (int j = 0; j < 4; ++j) {
                __builtin_amdgcn_global_load_lds(
                    (const __attribute__((address_space(1))) unsigned int*)(agl + j * 64),
                    (__attribute__((address_space(3))) unsigned int*)(sA + ns + (wave * 4 + j) * 512),
                    16, 0, 0);
            }
#pragma unroll
            for (int f = 0; f < 8; ++f)
                qwn[f] = wbase[(f >> 2) * 512 + (f & 3) * 16];
        }

        // prefetch scales for group+1 (used at it+2)
        if ((it & 1) == 0 && it + 2 < ITERS) {
            const size_t gbase =
                ((size_t)((kt0 + it) >> 1) + 1) * N_DIM + nrow0;
#pragma unroll
            for (int t = 0; t < 4; ++t)
                szn[t] = saz2[gbase + t * 16];
        }

        // compute: 2 k-steps of 32; dequant b-frags in registers
#pragma unroll
        for (int s01 = 0; s01 < 2; ++s01) {
#pragma unroll
            for (int j = 0; j < 4; ++j) {
                half8 bv = dequant8(qw[s01 * 4 + j], s2[j], z2[j]);
#pragma unroll
                for (int i = 0; i < 4; ++i)
                    acc[i][j] = __builtin_amdgcn_mfma_f32_16x16x32_f16(
                        av[i * 2 + s01], bv, acc[i][j], 0, 0, 0);
            }
        }

#pragma unroll
        for (int f = 0; f < 8; ++f) qw[f] = qwn[f];
    }

    // Epilogue: C/D layout col = lane&15 (n), row = q4*4 + reg (m).
    const int m0 = mbp * 64 + q4 * 4;
    const int n0 = npair * 128 + wave * 64 + lr;
#pragma unroll
    for (int i = 0; i < 4; ++i) {
#pragma unroll
        for (int j = 0; j < 4; ++j) {
            floatx4 v = acc[i][j];
            float* o = out + (size_t)(m0 + i * 16) * N_DIM + (n0 + j * 16);
#pragma unroll
            for (int rr = 0; rr < 4; ++rr)
                __hip_atomic_fetch_add(&o[(size_t)rr * N_DIM], v[rr],
                                       __ATOMIC_RELAXED, __HIP_MEMORY_SCOPE_AGENT);
        }
    }
}

extern "C" void kernel_launch(void* const* d_in, const int* in_sizes, int n_in,
                              void* d_out, int out_size, void* d_ws, size_t ws_size,
                              hipStream_t stream) {
    const float* x   = (const float*)d_in[0];
    const int*   wq  = (const int*)d_in[1];
    const float* saz = (const float*)d_in[2];

    // ws layout: [wpk: 22,544,384 B packed weights][xb: 4 MB f16 x]
    unsigned int* wpk = (unsigned int*)d_ws;
    unsigned int* xb  = (unsigned int*)((char*)d_ws + 22544384);

    hipMemsetAsync(d_out, 0, (size_t)out_size * sizeof(float), stream);
    pack_kernel<<<dim3(11008), dim3(256), 0, stream>>>(wq, wpk);
    cvt_kernel<<<dim3(1024), dim3(256), 0, stream>>>(x, xb);
    gemm_kernel<<<dim3(NBLK), dim3(128), 0, stream>>>(xb, wpk, saz, (float*)d_out);
}